// Round 1
// baseline (826.372 us; speedup 1.0000x reference)
//
#include <hip/hip_runtime.h>
#include <math.h>

#define N_NODES 100000
#define N_EDGES 1600000
#define IN_F 128
#define H_F 64

// workspace layout in 4-byte words (all offsets multiples of 64 words = 256B)
#define NP        100096                      // N_NODES rounded up to mult of 64
#define OFF_DEG   0                           // int[NP]
#define OFF_CUR   (NP)                        // int[NP]
#define OFF_DINV  (2*NP)                      // float[NP]
#define OFF_OFFS  (3*NP)                      // int[N+1] (NP+64 reserved)
#define OFF_ADJ   (4*NP + 64)                 // int[N_EDGES]
#define OFF_MCAT  (OFF_ADJ + N_EDGES)         // float[3*64*64]
#define OFF_BUFA  (OFF_MCAT + 12288)          // float[N*64]  (h1, later g2)
#define OFF_BUFB  (OFF_BUFA + N_NODES*H_F)    // float[N*64]  (g0)
#define OFF_BUFC  (OFF_BUFB + N_NODES*H_F)    // float[N*64]  (g1)

__device__ __forceinline__ float bcastf(float v, int l) {
    return __int_as_float(__builtin_amdgcn_readlane(__float_as_int(v), l));
}
__device__ __forceinline__ int bcasti(int v, int l) {
    return __builtin_amdgcn_readlane(v, l);
}

// ---- degree (in-degree over dst) ----
__global__ void k_deg(const int* __restrict__ dst, int* __restrict__ deg, int E) {
    int e = blockIdx.x * blockDim.x + threadIdx.x;
    if (e < E) atomicAdd(&deg[dst[e]], 1);
}

__global__ void k_dinv(const int* __restrict__ deg, float* __restrict__ dinv, int N) {
    int v = blockIdx.x * blockDim.x + threadIdx.x;
    if (v < N) {
        float d = (float)deg[v];
        dinv[v] = 1.0f / sqrtf(d < 1.0f ? 1.0f : d);
    }
}

// ---- exclusive prefix scan (single block, 1024 threads) ----
__global__ __launch_bounds__(1024) void k_scan(const int* __restrict__ deg,
                                               int* __restrict__ offs, int N) {
    __shared__ int sums[1024];
    int t = threadIdx.x;
    int chunk = (N + 1023) >> 10;
    int beg = t * chunk;
    int end = beg + chunk; if (end > N) end = N;
    int s = 0;
    for (int i = beg; i < end && i >= 0; ++i) s += deg[i];
    sums[t] = s;
    __syncthreads();
    for (int off = 1; off < 1024; off <<= 1) {
        int v = (t >= off) ? sums[t - off] : 0;
        __syncthreads();
        sums[t] += v;
        __syncthreads();
    }
    int run = (t == 0) ? 0 : sums[t - 1];
    for (int i = beg; i < end; ++i) { offs[i] = run; run += deg[i]; }
    if (t == 1023) offs[N] = sums[1023];
}

// ---- CSR fill ----
__global__ void k_fill(const int* __restrict__ src, const int* __restrict__ dst,
                       const int* __restrict__ offs, int* __restrict__ cur,
                       int* __restrict__ adj, int E) {
    int e = blockIdx.x * blockDim.x + threadIdx.x;
    if (e < E) {
        int d = dst[e];
        int p = atomicAdd(&cur[d], 1);
        adj[offs[d] + p] = src[e];
    }
}

// ---- GEMM1: h1 = relu(x @ W1 + b1), x: N x 128, W1: 128 x 64 ----
__global__ __launch_bounds__(256) void k_gemm1(const float* __restrict__ x,
        const float* __restrict__ W, const float* __restrict__ b,
        float* __restrict__ h, int N) {
    __shared__ float Wl[IN_F * H_F];
    int t = threadIdx.x;
    for (int i = t; i < IN_F * H_F; i += 256) Wl[i] = W[i];
    __syncthreads();
    int lane = t & 63;
    float bias = b[lane];
    int wid = blockIdx.x * 4 + (t >> 6);
    int nw = gridDim.x * 4;
    for (int n = wid; n < N; n += nw) {
        float xv0 = x[n * IN_F + lane];
        float xv1 = x[n * IN_F + 64 + lane];
        float acc = bias;
        #pragma unroll
        for (int c = 0; c < 64; ++c) acc = fmaf(bcastf(xv0, c), Wl[c * 64 + lane], acc);
        #pragma unroll
        for (int c = 0; c < 64; ++c) acc = fmaf(bcastf(xv1, c), Wl[(64 + c) * 64 + lane], acc);
        h[n * H_F + lane] = fmaxf(acc, 0.0f);
    }
}

// ---- GEMM2: g0 = relu(h1 @ W2 + b2), 64 x 64 ----
__global__ __launch_bounds__(256) void k_gemm2(const float* __restrict__ hin,
        const float* __restrict__ W, const float* __restrict__ b,
        float* __restrict__ hout, int N) {
    __shared__ float Wl[H_F * H_F];
    int t = threadIdx.x;
    for (int i = t; i < H_F * H_F; i += 256) Wl[i] = W[i];
    __syncthreads();
    int lane = t & 63;
    float bias = b[lane];
    int wid = blockIdx.x * 4 + (t >> 6);
    int nw = gridDim.x * 4;
    for (int n = wid; n < N; n += nw) {
        float hv = hin[n * H_F + lane];
        float acc = bias;
        #pragma unroll
        for (int c = 0; c < 64; ++c) acc = fmaf(bcastf(hv, c), Wl[c * 64 + lane], acc);
        hout[n * H_F + lane] = fmaxf(acc, 0.0f);
    }
}

// ---- propagation: fout = fin - dinv .* (A^T (dinv .* fin)) via CSR gather ----
__global__ __launch_bounds__(256) void k_prop(const float* __restrict__ fin,
        float* __restrict__ fout, const int* __restrict__ offs,
        const int* __restrict__ adj, const float* __restrict__ dinv, int N) {
    int lane = threadIdx.x & 63;
    int n = blockIdx.x * 4 + (threadIdx.x >> 6);
    if (n >= N) return;
    int beg = offs[n], end = offs[n + 1];
    float acc = 0.0f;
    for (int base = beg; base < end; base += 64) {
        int e = base + lane;
        int s = (e < end) ? adj[e] : 0;
        int cnt = end - base; if (cnt > 64) cnt = 64;
        for (int j = 0; j < cnt; ++j) {
            int sj = bcasti(s, j);
            acc = fmaf(dinv[sj], fin[sj * 64 + lane], acc);
        }
    }
    fout[n * 64 + lane] = fin[n * 64 + lane] - acc * dinv[n];
}

// ---- Mcat[k][c][o] = sum_i theta[i][k] * Wm1[(i*64+c)*64+o] ----
__global__ void k_mcat(const float* __restrict__ Wm1, float* __restrict__ Mcat) {
    int idx = blockIdx.x * blockDim.x + threadIdx.x;
    if (idx < 3 * 64 * 64) {
        int k = idx >> 12;
        int c = (idx >> 6) & 63;
        int o = idx & 63;
        const float TH[3][3] = {{3.f, -3.f, 0.75f}, {0.f, 3.f, -1.5f}, {0.f, 0.f, 0.75f}};
        float v = 0.f;
        #pragma unroll
        for (int i = 0; i < 3; ++i) v += TH[i][k] * Wm1[(i * 64 + c) * 64 + o];
        Mcat[idx] = v;
    }
}

// ---- final: out = relu(sum_k g_k @ M_k + bm1) @ Wm2 + bm2 ----
__global__ __launch_bounds__(256) void k_final(const float* __restrict__ g0,
        const float* __restrict__ g1, const float* __restrict__ g2,
        const float* __restrict__ Mcat, const float* __restrict__ bm1,
        const float* __restrict__ Wm2, const float* __restrict__ bm2,
        float* __restrict__ out, int N) {
    __shared__ float Ml[3 * 64 * 64];
    int t = threadIdx.x;
    for (int i = t; i < 3 * 64 * 64; i += 256) Ml[i] = Mcat[i];
    __syncthreads();
    int lane = t & 63;
    float bias = bm1[lane];
    float w0 = Wm2[lane * 2 + 0], w1 = Wm2[lane * 2 + 1];
    float bo0 = bm2[0], bo1 = bm2[1];
    int wid = blockIdx.x * 4 + (t >> 6);
    int nw = gridDim.x * 4;
    for (int n = wid; n < N; n += nw) {
        float v0 = g0[n * 64 + lane];
        float v1 = g1[n * 64 + lane];
        float v2 = g2[n * 64 + lane];
        float acc = bias;
        #pragma unroll
        for (int c = 0; c < 64; ++c) acc = fmaf(bcastf(v0, c), Ml[c * 64 + lane], acc);
        #pragma unroll
        for (int c = 0; c < 64; ++c) acc = fmaf(bcastf(v1, c), Ml[4096 + c * 64 + lane], acc);
        #pragma unroll
        for (int c = 0; c < 64; ++c) acc = fmaf(bcastf(v2, c), Ml[8192 + c * 64 + lane], acc);
        float hf = fmaxf(acc, 0.0f);
        float p0 = hf * w0, p1 = hf * w1;
        #pragma unroll
        for (int off = 32; off > 0; off >>= 1) {
            p0 += __shfl_down(p0, off);
            p1 += __shfl_down(p1, off);
        }
        if (lane == 0) { out[n * 2 + 0] = p0 + bo0; out[n * 2 + 1] = p1 + bo1; }
    }
}

extern "C" void kernel_launch(void* const* d_in, const int* in_sizes, int n_in,
                              void* d_out, int out_size, void* d_ws, size_t ws_size,
                              hipStream_t stream) {
    const float* x   = (const float*)d_in[0];
    const int*   ei  = (const int*)d_in[1];
    const float* W1  = (const float*)d_in[2];
    const float* b1  = (const float*)d_in[3];
    const float* W2  = (const float*)d_in[4];
    const float* b2  = (const float*)d_in[5];
    const float* Wm1 = (const float*)d_in[6];
    const float* bm1 = (const float*)d_in[7];
    const float* Wm2 = (const float*)d_in[8];
    const float* bm2 = (const float*)d_in[9];
    float* out = (float*)d_out;

    int* ws = (int*)d_ws;
    int*   deg  = ws + OFF_DEG;
    int*   cur  = ws + OFF_CUR;
    float* dinv = (float*)(ws + OFF_DINV);
    int*   offs = ws + OFF_OFFS;
    int*   adj  = ws + OFF_ADJ;
    float* Mcat = (float*)(ws + OFF_MCAT);
    float* bufA = (float*)(ws + OFF_BUFA);   // h1, later g2
    float* bufB = (float*)(ws + OFF_BUFB);   // g0
    float* bufC = (float*)(ws + OFF_BUFC);   // g1

    const int* srcp = ei;
    const int* dstp = ei + N_EDGES;

    // zero deg + cur (contiguous)
    hipMemsetAsync(deg, 0, 2 * NP * sizeof(int), stream);

    k_deg<<<(N_EDGES + 255) / 256, 256, 0, stream>>>(dstp, deg, N_EDGES);
    k_dinv<<<(N_NODES + 255) / 256, 256, 0, stream>>>(deg, dinv, N_NODES);
    k_scan<<<1, 1024, 0, stream>>>(deg, offs, N_NODES);
    k_fill<<<(N_EDGES + 255) / 256, 256, 0, stream>>>(srcp, dstp, offs, cur, adj, N_EDGES);

    k_gemm1<<<2048, 256, 0, stream>>>(x, W1, b1, bufA, N_NODES);
    k_gemm2<<<2048, 256, 0, stream>>>(bufA, W2, b2, bufB, N_NODES);   // g0 = bufB

    k_prop<<<(N_NODES + 3) / 4, 256, 0, stream>>>(bufB, bufC, offs, adj, dinv, N_NODES); // g1
    k_prop<<<(N_NODES + 3) / 4, 256, 0, stream>>>(bufC, bufA, offs, adj, dinv, N_NODES); // g2

    k_mcat<<<48, 256, 0, stream>>>(Wm1, Mcat);
    k_final<<<1536, 256, 0, stream>>>(bufB, bufC, bufA, Mcat, bm1, Wm2, bm2, out, N_NODES);
}

// Round 2
// 632.828 us; speedup vs baseline: 1.3058x; 1.3058x over previous
//
#include <hip/hip_runtime.h>
#include <math.h>

#define N_NODES 100000
#define N_EDGES 1600000
#define IN_F 128
#define H_F 64
#define NB_SCAN 98   // ceil(N_NODES/1024)

// workspace layout in 4-byte words
#define NP        100096                      // N_NODES rounded up to mult of 64
#define OFF_DEG   0                           // int[NP]
#define OFF_CUR   (NP)                        // int[NP]
#define OFF_OFFS  (2*NP)                      // int[N+1] (NP+64 reserved)
#define OFF_BSUM  (3*NP + 64)                 // int[192]
#define OFF_D2    (3*NP + 256)                // float[NP]  dinv^2
#define OFF_RD    (4*NP + 256)                // float[NP]  sqrt(clip(deg,1))
#define OFF_DINV  (5*NP + 256)                // float[NP]  1/sqrt(clip(deg,1))
#define OFF_ADJ   (6*NP + 256)                // int[N_EDGES]
#define OFF_BUFA  (OFF_ADJ + N_EDGES)         // float[N*64]  h1, later gs2
#define OFF_BUFB  (OFF_BUFA + N_NODES*H_F)    // float[N*64]  gs0
#define OFF_BUFC  (OFF_BUFB + N_NODES*H_F)    // float[N*64]  gs1

__device__ __forceinline__ float bcastf(float v, int l) {
    return __int_as_float(__builtin_amdgcn_readlane(__float_as_int(v), l));
}
__device__ __forceinline__ int bcasti(int v, int l) {
    return __builtin_amdgcn_readlane(v, l);
}

// ---- in-degree over dst ----
__global__ void k_deg(const int* __restrict__ dst, int* __restrict__ deg, int E) {
    int e = blockIdx.x * blockDim.x + threadIdx.x;
    if (e < E) atomicAdd(&deg[dst[e]], 1);
}

// ---- scan phase A: per-block (1024-elem tile) exclusive scan + block sums ----
__global__ __launch_bounds__(256) void k_scan_a(const int* __restrict__ deg,
        int* __restrict__ offs, int* __restrict__ bsum) {
    __shared__ int wsum[4];
    int t = threadIdx.x, b = blockIdx.x;
    int lane = t & 63, wid = t >> 6;
    int base = b * 1024 + t * 4;
    int d0 = (base + 0 < N_NODES) ? deg[base + 0] : 0;
    int d1 = (base + 1 < N_NODES) ? deg[base + 1] : 0;
    int d2v = (base + 2 < N_NODES) ? deg[base + 2] : 0;
    int d3 = (base + 3 < N_NODES) ? deg[base + 3] : 0;
    int tot = d0 + d1 + d2v + d3;
    int inc = tot;
    #pragma unroll
    for (int off = 1; off < 64; off <<= 1) {
        int v = __shfl_up(inc, off, 64);
        if (lane >= off) inc += v;
    }
    if (lane == 63) wsum[wid] = inc;
    __syncthreads();
    int wbase = 0;
    for (int w = 0; w < wid; ++w) wbase += wsum[w];
    int excl = wbase + inc - tot;
    if (base + 0 < N_NODES) offs[base + 0] = excl; excl += d0;
    if (base + 1 < N_NODES) offs[base + 1] = excl; excl += d1;
    if (base + 2 < N_NODES) offs[base + 2] = excl; excl += d2v;
    if (base + 3 < N_NODES) offs[base + 3] = excl; excl += d3;
    if (t == 255) bsum[b] = wbase + inc;
}

// ---- scan phase B: scan the 98 block sums ----
__global__ __launch_bounds__(128) void k_scan_b(int* __restrict__ bsum,
                                                int* __restrict__ offs) {
    __shared__ int sm[128];
    int t = threadIdx.x;
    int v = (t < NB_SCAN) ? bsum[t] : 0;
    sm[t] = v;
    __syncthreads();
    #pragma unroll
    for (int off = 1; off < 128; off <<= 1) {
        int u = (t >= off) ? sm[t - off] : 0;
        __syncthreads();
        sm[t] += u;
        __syncthreads();
    }
    if (t < NB_SCAN) bsum[t] = (t == 0) ? 0 : sm[t - 1];
    if (t == 0) offs[N_NODES] = N_EDGES;   // total in-degree == edge count
}

// ---- scan phase C: add block bases, copy to cur, compute d2/rd/dinv ----
__global__ __launch_bounds__(256) void k_scan_c(const int* __restrict__ deg,
        int* __restrict__ offs, const int* __restrict__ bsum, int* __restrict__ cur,
        float* __restrict__ d2a, float* __restrict__ rda, float* __restrict__ dinva) {
    int b = blockIdx.x, t = threadIdx.x;
    int add = bsum[b];
    int base = b * 1024 + t * 4;
    #pragma unroll
    for (int i = 0; i < 4; ++i) {
        int idx = base + i;
        if (idx < N_NODES) {
            int o = offs[idx] + add;
            offs[idx] = o;
            cur[idx] = o;
            float dd = (float)deg[idx];
            if (dd < 1.f) dd = 1.f;
            float di = 1.0f / sqrtf(dd);
            dinva[idx] = di;
            d2a[idx] = di * di;
            rda[idx] = sqrtf(dd);
        }
    }
}

// ---- CSR fill (cur pre-seeded with offs) ----
__global__ void k_fill(const int* __restrict__ src, const int* __restrict__ dst,
                       int* __restrict__ cur, int* __restrict__ adj, int E) {
    int e = blockIdx.x * blockDim.x + threadIdx.x;
    if (e < E) {
        int d = dst[e];
        int p = atomicAdd(&cur[d], 1);
        adj[p] = src[e];
    }
}

// ---- GEMM1: h1 = relu(x @ W1 + b1) ----
__global__ __launch_bounds__(256) void k_gemm1(const float* __restrict__ x,
        const float* __restrict__ W, const float* __restrict__ b,
        float* __restrict__ h, int N) {
    __shared__ float Wl[IN_F * H_F];
    int t = threadIdx.x;
    for (int i = t; i < IN_F * H_F; i += 256) Wl[i] = W[i];
    __syncthreads();
    int lane = t & 63;
    float bias = b[lane];
    int wid = blockIdx.x * 4 + (t >> 6);
    int nw = gridDim.x * 4;
    for (int n = wid; n < N; n += nw) {
        float xv0 = x[n * IN_F + lane];
        float xv1 = x[n * IN_F + 64 + lane];
        float acc = bias;
        #pragma unroll
        for (int c = 0; c < 64; ++c) acc = fmaf(bcastf(xv0, c), Wl[c * 64 + lane], acc);
        #pragma unroll
        for (int c = 0; c < 64; ++c) acc = fmaf(bcastf(xv1, c), Wl[(64 + c) * 64 + lane], acc);
        h[n * H_F + lane] = fmaxf(acc, 0.0f);
    }
}

// ---- GEMM2: gs0 = dinv .* relu(h1 @ W2 + b2)  (scaled-space output) ----
__global__ __launch_bounds__(256) void k_gemm2s(const float* __restrict__ hin,
        const float* __restrict__ W, const float* __restrict__ b,
        const float* __restrict__ dinva, float* __restrict__ gs, int N) {
    __shared__ float Wl[H_F * H_F];
    int t = threadIdx.x;
    for (int i = t; i < H_F * H_F; i += 256) Wl[i] = W[i];
    __syncthreads();
    int lane = t & 63;
    float bias = b[lane];
    int wid = blockIdx.x * 4 + (t >> 6);
    int nw = gridDim.x * 4;
    for (int n = wid; n < N; n += nw) {
        float hv = hin[n * H_F + lane];
        float acc = bias;
        #pragma unroll
        for (int c = 0; c < 64; ++c) acc = fmaf(bcastf(hv, c), Wl[c * 64 + lane], acc);
        gs[n * H_F + lane] = dinva[n] * fmaxf(acc, 0.0f);
    }
}

// ---- propagation in scaled space: gs_out = gs - d2[n] * sum_src gs[src] ----
// unroll x8 gathers for memory-level parallelism
__global__ __launch_bounds__(256) void k_prop(const float* __restrict__ gs,
        float* __restrict__ gsn, const int* __restrict__ offs,
        const int* __restrict__ adj, const float* __restrict__ d2a, int N) {
    int lane = threadIdx.x & 63;
    int n = blockIdx.x * 4 + (threadIdx.x >> 6);
    if (n >= N) return;
    int beg = offs[n], end = offs[n + 1];
    float self = gs[n * 64 + lane];
    float d2n = d2a[n];
    float acc = 0.0f;
    for (int base = beg; base < end; base += 64) {
        int e = base + lane;
        int s = (e < end) ? adj[e] : 0;
        int cnt = end - base; if (cnt > 64) cnt = 64;
        int j = 0;
        for (; j + 8 <= cnt; j += 8) {
            int s0 = bcasti(s, j + 0), s1 = bcasti(s, j + 1);
            int s2 = bcasti(s, j + 2), s3 = bcasti(s, j + 3);
            int s4 = bcasti(s, j + 4), s5 = bcasti(s, j + 5);
            int s6 = bcasti(s, j + 6), s7 = bcasti(s, j + 7);
            float f0 = gs[s0 * 64 + lane], f1 = gs[s1 * 64 + lane];
            float f2 = gs[s2 * 64 + lane], f3 = gs[s3 * 64 + lane];
            float f4 = gs[s4 * 64 + lane], f5 = gs[s5 * 64 + lane];
            float f6 = gs[s6 * 64 + lane], f7 = gs[s7 * 64 + lane];
            acc += ((f0 + f1) + (f2 + f3)) + ((f4 + f5) + (f6 + f7));
        }
        for (; j < cnt; ++j) {
            int sj = bcasti(s, j);
            acc += gs[sj * 64 + lane];
        }
    }
    gsn[n * 64 + lane] = fmaf(-d2n, acc, self);
}

// ---- final: out = relu((sum_k rd.*gs_k @ M_k) + bm1) @ Wm2 + bm2 ----
// M_k folded from Wm1 & thetas in LDS; rd factored out of the matmul.
__global__ __launch_bounds__(256) void k_final(const float* __restrict__ gs0,
        const float* __restrict__ gs1, const float* __restrict__ gs2,
        const float* __restrict__ Wm1, const float* __restrict__ bm1,
        const float* __restrict__ Wm2, const float* __restrict__ bm2,
        const float* __restrict__ rda, float* __restrict__ out, int N) {
    __shared__ float Ml[3 * 64 * 64];
    int t = threadIdx.x;
    // Ml[k*4096 + c*64 + o] = sum_i theta[i][k] * Wm1[(i*64+c)*64+o]
    for (int i = t; i < 3 * 4096; i += 256) {
        int k = i >> 12, rem = i & 4095;
        int c = rem >> 6, o = rem & 63;
        float w0 = Wm1[c * 64 + o];
        float w1 = Wm1[(64 + c) * 64 + o];
        float w2 = Wm1[(128 + c) * 64 + o];
        float v;
        if (k == 0)      v = 3.0f * w0;
        else if (k == 1) v = fmaf(-3.0f, w0, 3.0f * w1);
        else             v = 0.75f * w0 + fmaf(-1.5f, w1, 0.75f * w2);
        Ml[i] = v;
    }
    __syncthreads();
    int lane = t & 63;
    float bias = bm1[lane];
    float w0 = Wm2[lane * 2 + 0], w1 = Wm2[lane * 2 + 1];
    float bo0 = bm2[0], bo1 = bm2[1];
    int wid = blockIdx.x * 4 + (t >> 6);
    int nw = gridDim.x * 4;
    for (int n = wid; n < N; n += nw) {
        float v0 = gs0[n * 64 + lane];
        float v1 = gs1[n * 64 + lane];
        float v2 = gs2[n * 64 + lane];
        float rdn = rda[n];
        float acc = 0.0f;
        #pragma unroll
        for (int c = 0; c < 64; ++c) acc = fmaf(bcastf(v0, c), Ml[c * 64 + lane], acc);
        #pragma unroll
        for (int c = 0; c < 64; ++c) acc = fmaf(bcastf(v1, c), Ml[4096 + c * 64 + lane], acc);
        #pragma unroll
        for (int c = 0; c < 64; ++c) acc = fmaf(bcastf(v2, c), Ml[8192 + c * 64 + lane], acc);
        float hf = fmaxf(fmaf(acc, rdn, bias), 0.0f);
        float p0 = hf * w0, p1 = hf * w1;
        #pragma unroll
        for (int off = 32; off > 0; off >>= 1) {
            p0 += __shfl_down(p0, off);
            p1 += __shfl_down(p1, off);
        }
        if (lane == 0) { out[n * 2 + 0] = p0 + bo0; out[n * 2 + 1] = p1 + bo1; }
    }
}

extern "C" void kernel_launch(void* const* d_in, const int* in_sizes, int n_in,
                              void* d_out, int out_size, void* d_ws, size_t ws_size,
                              hipStream_t stream) {
    const float* x   = (const float*)d_in[0];
    const int*   ei  = (const int*)d_in[1];
    const float* W1  = (const float*)d_in[2];
    const float* b1  = (const float*)d_in[3];
    const float* W2  = (const float*)d_in[4];
    const float* b2  = (const float*)d_in[5];
    const float* Wm1 = (const float*)d_in[6];
    const float* bm1 = (const float*)d_in[7];
    const float* Wm2 = (const float*)d_in[8];
    const float* bm2 = (const float*)d_in[9];
    float* out = (float*)d_out;

    int* ws = (int*)d_ws;
    int*   deg  = ws + OFF_DEG;
    int*   cur  = ws + OFF_CUR;
    int*   offs = ws + OFF_OFFS;
    int*   bsum = ws + OFF_BSUM;
    float* d2a  = (float*)(ws + OFF_D2);
    float* rda  = (float*)(ws + OFF_RD);
    float* dinva= (float*)(ws + OFF_DINV);
    int*   adj  = ws + OFF_ADJ;
    float* bufA = (float*)(ws + OFF_BUFA);   // h1, later gs2
    float* bufB = (float*)(ws + OFF_BUFB);   // gs0
    float* bufC = (float*)(ws + OFF_BUFC);   // gs1

    const int* srcp = ei;
    const int* dstp = ei + N_EDGES;

    hipMemsetAsync(deg, 0, NP * sizeof(int), stream);

    k_deg<<<(N_EDGES + 255) / 256, 256, 0, stream>>>(dstp, deg, N_EDGES);
    k_scan_a<<<NB_SCAN, 256, 0, stream>>>(deg, offs, bsum);
    k_scan_b<<<1, 128, 0, stream>>>(bsum, offs);
    k_scan_c<<<NB_SCAN, 256, 0, stream>>>(deg, offs, bsum, cur, d2a, rda, dinva);
    k_fill<<<(N_EDGES + 255) / 256, 256, 0, stream>>>(srcp, dstp, cur, adj, N_EDGES);

    k_gemm1<<<2048, 256, 0, stream>>>(x, W1, b1, bufA, N_NODES);
    k_gemm2s<<<2048, 256, 0, stream>>>(bufA, W2, b2, dinva, bufB, N_NODES);  // gs0

    k_prop<<<(N_NODES + 3) / 4, 256, 0, stream>>>(bufB, bufC, offs, adj, d2a, N_NODES); // gs1
    k_prop<<<(N_NODES + 3) / 4, 256, 0, stream>>>(bufC, bufA, offs, adj, d2a, N_NODES); // gs2

    k_final<<<1536, 256, 0, stream>>>(bufB, bufC, bufA, Wm1, bm1, Wm2, bm2, rda, out, N_NODES);
}

// Round 3
// 515.070 us; speedup vs baseline: 1.6044x; 1.2286x over previous
//
#include <hip/hip_runtime.h>
#include <math.h>

#define N_NODES 100000
#define N_EDGES 1600000
#define IN_F 128
#define H_F 64
#define NB_SCAN 98   // ceil(N_NODES/1024)
#define KP 68        // padded LDS leading dim for A tiles

// workspace layout in 4-byte words
#define NP        100096                      // N_NODES rounded up to mult of 64
#define OFF_DEG   0                           // int[NP]
#define OFF_CUR   (NP)                        // int[NP]
#define OFF_OFFS  (2*NP)                      // int[N+1] (NP+64 reserved)
#define OFF_BSUM  (3*NP + 64)                 // int[192]
#define OFF_D2    (3*NP + 256)                // float[NP]  dinv^2
#define OFF_RD    (4*NP + 256)                // float[NP]  sqrt(clip(deg,1))
#define OFF_DINV  (5*NP + 256)                // float[NP]  1/sqrt(clip(deg,1))
#define OFF_ADJ   (6*NP + 256)                // int[N_EDGES]
#define OFF_BUFA  (OFF_ADJ + N_EDGES)         // float[N*64]  h1, later gs2
#define OFF_BUFB  (OFF_BUFA + N_NODES*H_F)    // float[N*64]  gs0
#define OFF_BUFC  (OFF_BUFB + N_NODES*H_F)    // float[N*64]  gs1

// ---- in-degree over dst ----
__global__ void k_deg(const int* __restrict__ dst, int* __restrict__ deg, int E) {
    int e = blockIdx.x * blockDim.x + threadIdx.x;
    if (e < E) atomicAdd(&deg[dst[e]], 1);
}

// ---- scan phase A ----
__global__ __launch_bounds__(256) void k_scan_a(const int* __restrict__ deg,
        int* __restrict__ offs, int* __restrict__ bsum) {
    __shared__ int wsum[4];
    int t = threadIdx.x, b = blockIdx.x;
    int lane = t & 63, wid = t >> 6;
    int base = b * 1024 + t * 4;
    int d0 = (base + 0 < N_NODES) ? deg[base + 0] : 0;
    int d1 = (base + 1 < N_NODES) ? deg[base + 1] : 0;
    int d2v = (base + 2 < N_NODES) ? deg[base + 2] : 0;
    int d3 = (base + 3 < N_NODES) ? deg[base + 3] : 0;
    int tot = d0 + d1 + d2v + d3;
    int inc = tot;
    #pragma unroll
    for (int off = 1; off < 64; off <<= 1) {
        int v = __shfl_up(inc, off, 64);
        if (lane >= off) inc += v;
    }
    if (lane == 63) wsum[wid] = inc;
    __syncthreads();
    int wbase = 0;
    for (int w = 0; w < wid; ++w) wbase += wsum[w];
    int excl = wbase + inc - tot;
    if (base + 0 < N_NODES) offs[base + 0] = excl; excl += d0;
    if (base + 1 < N_NODES) offs[base + 1] = excl; excl += d1;
    if (base + 2 < N_NODES) offs[base + 2] = excl; excl += d2v;
    if (base + 3 < N_NODES) offs[base + 3] = excl; excl += d3;
    if (t == 255) bsum[b] = wbase + inc;
}

// ---- scan phase B ----
__global__ __launch_bounds__(128) void k_scan_b(int* __restrict__ bsum,
                                                int* __restrict__ offs) {
    __shared__ int sm[128];
    int t = threadIdx.x;
    int v = (t < NB_SCAN) ? bsum[t] : 0;
    sm[t] = v;
    __syncthreads();
    #pragma unroll
    for (int off = 1; off < 128; off <<= 1) {
        int u = (t >= off) ? sm[t - off] : 0;
        __syncthreads();
        sm[t] += u;
        __syncthreads();
    }
    if (t < NB_SCAN) bsum[t] = (t == 0) ? 0 : sm[t - 1];
    if (t == 0) offs[N_NODES] = N_EDGES;
}

// ---- scan phase C: add bases, seed cur, derive d2/rd/dinv ----
__global__ __launch_bounds__(256) void k_scan_c(const int* __restrict__ deg,
        int* __restrict__ offs, const int* __restrict__ bsum, int* __restrict__ cur,
        float* __restrict__ d2a, float* __restrict__ rda, float* __restrict__ dinva) {
    int b = blockIdx.x, t = threadIdx.x;
    int add = bsum[b];
    int base = b * 1024 + t * 4;
    #pragma unroll
    for (int i = 0; i < 4; ++i) {
        int idx = base + i;
        if (idx < N_NODES) {
            int o = offs[idx] + add;
            offs[idx] = o;
            cur[idx] = o;
            float dd = (float)deg[idx];
            if (dd < 1.f) dd = 1.f;
            float di = 1.0f / sqrtf(dd);
            dinva[idx] = di;
            d2a[idx] = di * di;
            rda[idx] = sqrtf(dd);
        }
    }
}

// ---- CSR fill ----
__global__ void k_fill(const int* __restrict__ src, const int* __restrict__ dst,
                       int* __restrict__ cur, int* __restrict__ adj, int E) {
    int e = blockIdx.x * blockDim.x + threadIdx.x;
    if (e < E) {
        int d = dst[e];
        int p = atomicAdd(&cur[d], 1);
        adj[p] = src[e];
    }
}

// ================= tiled GEMMs: 64 nodes x 64 outs per 256-thr block ========
// thread (tx=t&15, ty=t>>4) computes C[4ty..4ty+3][4tx..4tx+3]

// GEMM1: h = relu(x @ W1 + b1), K=128 in 2 phases
__global__ __launch_bounds__(256) void k_gemm1(const float* __restrict__ x,
        const float* __restrict__ W, const float* __restrict__ b,
        float* __restrict__ h, int N) {
    __shared__ float Al[64 * KP];
    __shared__ float Bl[64 * 64];
    int t = threadIdx.x;
    int tx = t & 15, ty = t >> 4;
    int nb = blockIdx.x * 64;
    float acc[4][4] = {{0}};
    for (int p = 0; p < 2; ++p) {
        // fill A: 64 nodes x 64 k  (coalesced float4, transposed-free layout)
        #pragma unroll
        for (int pp = 0; pp < 4; ++pp) {
            int nl = ty + 16 * pp;
            int nn = nb + nl; if (nn >= N) nn = N - 1;
            float4 v = ((const float4*)(x + (size_t)nn * IN_F + p * 64))[tx];
            *(float4*)&Al[nl * KP + 4 * tx] = v;
        }
        // fill B: W1 rows p*64 .. p*64+63
        #pragma unroll
        for (int pp = 0; pp < 4; ++pp) {
            int k = ty + 16 * pp;
            float4 v = ((const float4*)(W + (size_t)(p * 64 + k) * 64))[tx];
            *(float4*)&Bl[k * 64 + 4 * tx] = v;
        }
        __syncthreads();
        #pragma unroll 4
        for (int k = 0; k < 64; ++k) {
            float a0 = Al[(4 * ty + 0) * KP + k];
            float a1 = Al[(4 * ty + 1) * KP + k];
            float a2 = Al[(4 * ty + 2) * KP + k];
            float a3 = Al[(4 * ty + 3) * KP + k];
            float4 bv = *(const float4*)&Bl[k * 64 + 4 * tx];
            acc[0][0] = fmaf(a0, bv.x, acc[0][0]); acc[0][1] = fmaf(a0, bv.y, acc[0][1]);
            acc[0][2] = fmaf(a0, bv.z, acc[0][2]); acc[0][3] = fmaf(a0, bv.w, acc[0][3]);
            acc[1][0] = fmaf(a1, bv.x, acc[1][0]); acc[1][1] = fmaf(a1, bv.y, acc[1][1]);
            acc[1][2] = fmaf(a1, bv.z, acc[1][2]); acc[1][3] = fmaf(a1, bv.w, acc[1][3]);
            acc[2][0] = fmaf(a2, bv.x, acc[2][0]); acc[2][1] = fmaf(a2, bv.y, acc[2][1]);
            acc[2][2] = fmaf(a2, bv.z, acc[2][2]); acc[2][3] = fmaf(a2, bv.w, acc[2][3]);
            acc[3][0] = fmaf(a3, bv.x, acc[3][0]); acc[3][1] = fmaf(a3, bv.y, acc[3][1]);
            acc[3][2] = fmaf(a3, bv.z, acc[3][2]); acc[3][3] = fmaf(a3, bv.w, acc[3][3]);
        }
        __syncthreads();
    }
    float4 bias = ((const float4*)b)[tx];
    #pragma unroll
    for (int i = 0; i < 4; ++i) {
        int n = nb + 4 * ty + i;
        if (n < N) {
            float4 r;
            r.x = fmaxf(acc[i][0] + bias.x, 0.f);
            r.y = fmaxf(acc[i][1] + bias.y, 0.f);
            r.z = fmaxf(acc[i][2] + bias.z, 0.f);
            r.w = fmaxf(acc[i][3] + bias.w, 0.f);
            ((float4*)(h + (size_t)n * 64))[tx] = r;
        }
    }
}

// GEMM2: gs0 = dinv .* relu(h @ W2 + b2), K=64
__global__ __launch_bounds__(256) void k_gemm2s(const float* __restrict__ hin,
        const float* __restrict__ W, const float* __restrict__ b,
        const float* __restrict__ dinva, float* __restrict__ gs, int N) {
    __shared__ float Al[64 * KP];
    __shared__ float Bl[64 * 64];
    int t = threadIdx.x;
    int tx = t & 15, ty = t >> 4;
    int nb = blockIdx.x * 64;
    float acc[4][4] = {{0}};
    #pragma unroll
    for (int pp = 0; pp < 4; ++pp) {
        int nl = ty + 16 * pp;
        int nn = nb + nl; if (nn >= N) nn = N - 1;
        float4 v = ((const float4*)(hin + (size_t)nn * 64))[tx];
        *(float4*)&Al[nl * KP + 4 * tx] = v;
        int k = nl;
        float4 w = ((const float4*)(W + (size_t)k * 64))[tx];
        *(float4*)&Bl[k * 64 + 4 * tx] = w;
    }
    __syncthreads();
    #pragma unroll 4
    for (int k = 0; k < 64; ++k) {
        float a0 = Al[(4 * ty + 0) * KP + k];
        float a1 = Al[(4 * ty + 1) * KP + k];
        float a2 = Al[(4 * ty + 2) * KP + k];
        float a3 = Al[(4 * ty + 3) * KP + k];
        float4 bv = *(const float4*)&Bl[k * 64 + 4 * tx];
        acc[0][0] = fmaf(a0, bv.x, acc[0][0]); acc[0][1] = fmaf(a0, bv.y, acc[0][1]);
        acc[0][2] = fmaf(a0, bv.z, acc[0][2]); acc[0][3] = fmaf(a0, bv.w, acc[0][3]);
        acc[1][0] = fmaf(a1, bv.x, acc[1][0]); acc[1][1] = fmaf(a1, bv.y, acc[1][1]);
        acc[1][2] = fmaf(a1, bv.z, acc[1][2]); acc[1][3] = fmaf(a1, bv.w, acc[1][3]);
        acc[2][0] = fmaf(a2, bv.x, acc[2][0]); acc[2][1] = fmaf(a2, bv.y, acc[2][1]);
        acc[2][2] = fmaf(a2, bv.z, acc[2][2]); acc[2][3] = fmaf(a2, bv.w, acc[2][3]);
        acc[3][0] = fmaf(a3, bv.x, acc[3][0]); acc[3][1] = fmaf(a3, bv.y, acc[3][1]);
        acc[3][2] = fmaf(a3, bv.z, acc[3][2]); acc[3][3] = fmaf(a3, bv.w, acc[3][3]);
    }
    float4 bias = ((const float4*)b)[tx];
    #pragma unroll
    for (int i = 0; i < 4; ++i) {
        int n = nb + 4 * ty + i;
        if (n < N) {
            float di = dinva[n];
            float4 r;
            r.x = di * fmaxf(acc[i][0] + bias.x, 0.f);
            r.y = di * fmaxf(acc[i][1] + bias.y, 0.f);
            r.z = di * fmaxf(acc[i][2] + bias.z, 0.f);
            r.w = di * fmaxf(acc[i][3] + bias.w, 0.f);
            ((float4*)(gs + (size_t)n * 64))[tx] = r;
        }
    }
}

// ---- propagation: gs_out = gs - d2[n] * sum_src gs[src] ----
// 4 edges per wave-iteration: lane group g=lane>>4 handles edge base+g,
// each group loads a float4 quarter-row; cross-group shfl_xor reduce.
__global__ __launch_bounds__(256) void k_prop(const float* __restrict__ gs,
        float* __restrict__ gsn, const int* __restrict__ offs,
        const int* __restrict__ adj, const float* __restrict__ d2a, int N) {
    int t = threadIdx.x;
    int lane = t & 63;
    int g = lane >> 4;
    int q = lane & 15;
    int n = blockIdx.x * 4 + (t >> 6);
    if (n >= N) return;
    int beg = offs[n], end = offs[n + 1];
    const float4* gs4 = (const float4*)gs;
    float ax = 0.f, ay = 0.f, az = 0.f, aw = 0.f;
    for (int e = beg + g; e < end; e += 4) {
        int s = adj[e];
        float4 f = gs4[(size_t)s * 16 + q];
        ax += f.x; ay += f.y; az += f.z; aw += f.w;
    }
    ax += __shfl_xor(ax, 16); ay += __shfl_xor(ay, 16);
    az += __shfl_xor(az, 16); aw += __shfl_xor(aw, 16);
    ax += __shfl_xor(ax, 32); ay += __shfl_xor(ay, 32);
    az += __shfl_xor(az, 32); aw += __shfl_xor(aw, 32);
    if (g == 0) {
        float d2n = d2a[n];
        float4 self = gs4[(size_t)n * 16 + q];
        float4 r;
        r.x = fmaf(-d2n, ax, self.x);
        r.y = fmaf(-d2n, ay, self.y);
        r.z = fmaf(-d2n, az, self.z);
        r.w = fmaf(-d2n, aw, self.w);
        ((float4*)gsn)[(size_t)n * 16 + q] = r;
    }
}

// ---- final: out = relu((sum_k rd.*gs_k @ M_k) + bm1) @ Wm2 + bm2 ----
// 3 K-phases (one per gs buffer); B tile = theta-combined Wm1 slice.
__global__ __launch_bounds__(256) void k_final(const float* __restrict__ gs0,
        const float* __restrict__ gs1, const float* __restrict__ gs2,
        const float* __restrict__ Wm1, const float* __restrict__ bm1,
        const float* __restrict__ Wm2, const float* __restrict__ bm2,
        const float* __restrict__ rda, float* __restrict__ out, int N) {
    __shared__ float Al[64 * KP];
    __shared__ float Bl[64 * 64];
    int t = threadIdx.x;
    int tx = t & 15, ty = t >> 4;
    int nb = blockIdx.x * 64;
    const float* bufs[3] = {gs0, gs1, gs2};
    float acc[4][4] = {{0}};
    for (int p = 0; p < 3; ++p) {
        const float* gp = bufs[p];
        #pragma unroll
        for (int pp = 0; pp < 4; ++pp) {
            int nl = ty + 16 * pp;
            int nn = nb + nl; if (nn >= N) nn = N - 1;
            float4 v = ((const float4*)(gp + (size_t)nn * 64))[tx];
            *(float4*)&Al[nl * KP + 4 * tx] = v;
            // B: M_p[k][o] = sum_i TH[i][p] * Wm1[(i*64+k)*64+o]
            int k = nl;
            float4 w0 = ((const float4*)(Wm1 + (size_t)k * 64))[tx];
            float4 w1 = ((const float4*)(Wm1 + (size_t)(64 + k) * 64))[tx];
            float4 w2 = ((const float4*)(Wm1 + (size_t)(128 + k) * 64))[tx];
            float4 mv;
            if (p == 0) {
                mv.x = 3.0f * w0.x; mv.y = 3.0f * w0.y;
                mv.z = 3.0f * w0.z; mv.w = 3.0f * w0.w;
            } else if (p == 1) {
                mv.x = fmaf(-3.0f, w0.x, 3.0f * w1.x);
                mv.y = fmaf(-3.0f, w0.y, 3.0f * w1.y);
                mv.z = fmaf(-3.0f, w0.z, 3.0f * w1.z);
                mv.w = fmaf(-3.0f, w0.w, 3.0f * w1.w);
            } else {
                mv.x = 0.75f * (w0.x + w2.x) - 1.5f * w1.x;
                mv.y = 0.75f * (w0.y + w2.y) - 1.5f * w1.y;
                mv.z = 0.75f * (w0.z + w2.z) - 1.5f * w1.z;
                mv.w = 0.75f * (w0.w + w2.w) - 1.5f * w1.w;
            }
            *(float4*)&Bl[k * 64 + 4 * tx] = mv;
        }
        __syncthreads();
        #pragma unroll 4
        for (int k = 0; k < 64; ++k) {
            float a0 = Al[(4 * ty + 0) * KP + k];
            float a1 = Al[(4 * ty + 1) * KP + k];
            float a2 = Al[(4 * ty + 2) * KP + k];
            float a3 = Al[(4 * ty + 3) * KP + k];
            float4 bv = *(const float4*)&Bl[k * 64 + 4 * tx];
            acc[0][0] = fmaf(a0, bv.x, acc[0][0]); acc[0][1] = fmaf(a0, bv.y, acc[0][1]);
            acc[0][2] = fmaf(a0, bv.z, acc[0][2]); acc[0][3] = fmaf(a0, bv.w, acc[0][3]);
            acc[1][0] = fmaf(a1, bv.x, acc[1][0]); acc[1][1] = fmaf(a1, bv.y, acc[1][1]);
            acc[1][2] = fmaf(a1, bv.z, acc[1][2]); acc[1][3] = fmaf(a1, bv.w, acc[1][3]);
            acc[2][0] = fmaf(a2, bv.x, acc[2][0]); acc[2][1] = fmaf(a2, bv.y, acc[2][1]);
            acc[2][2] = fmaf(a2, bv.z, acc[2][2]); acc[2][3] = fmaf(a2, bv.w, acc[2][3]);
            acc[3][0] = fmaf(a3, bv.x, acc[3][0]); acc[3][1] = fmaf(a3, bv.y, acc[3][1]);
            acc[3][2] = fmaf(a3, bv.z, acc[3][2]); acc[3][3] = fmaf(a3, bv.w, acc[3][3]);
        }
        __syncthreads();
    }
    // epilogue: hf = relu(rd*acc + bm1); partial dot with Wm2; reduce over tx
    float4 bmv = ((const float4*)bm1)[tx];
    float4 wa = ((const float4*)Wm2)[2 * tx];       // rows 4tx, 4tx+1
    float4 wb = ((const float4*)Wm2)[2 * tx + 1];   // rows 4tx+2, 4tx+3
    float bo0 = bm2[0], bo1 = bm2[1];
    #pragma unroll
    for (int i = 0; i < 4; ++i) {
        int n = nb + 4 * ty + i;
        float rdn = rda[(n < N) ? n : (N - 1)];
        float h0 = fmaxf(fmaf(rdn, acc[i][0], bmv.x), 0.f);
        float h1 = fmaxf(fmaf(rdn, acc[i][1], bmv.y), 0.f);
        float h2 = fmaxf(fmaf(rdn, acc[i][2], bmv.z), 0.f);
        float h3 = fmaxf(fmaf(rdn, acc[i][3], bmv.w), 0.f);
        float p0 = h0 * wa.x + h1 * wa.z + h2 * wb.x + h3 * wb.z;
        float p1 = h0 * wa.y + h1 * wa.w + h2 * wb.y + h3 * wb.w;
        #pragma unroll
        for (int m = 1; m < 16; m <<= 1) {
            p0 += __shfl_xor(p0, m);
            p1 += __shfl_xor(p1, m);
        }
        if (tx == 0 && n < N) {
            out[(size_t)n * 2 + 0] = p0 + bo0;
            out[(size_t)n * 2 + 1] = p1 + bo1;
        }
    }
}

extern "C" void kernel_launch(void* const* d_in, const int* in_sizes, int n_in,
                              void* d_out, int out_size, void* d_ws, size_t ws_size,
                              hipStream_t stream) {
    const float* x   = (const float*)d_in[0];
    const int*   ei  = (const int*)d_in[1];
    const float* W1  = (const float*)d_in[2];
    const float* b1  = (const float*)d_in[3];
    const float* W2  = (const float*)d_in[4];
    const float* b2  = (const float*)d_in[5];
    const float* Wm1 = (const float*)d_in[6];
    const float* bm1 = (const float*)d_in[7];
    const float* Wm2 = (const float*)d_in[8];
    const float* bm2 = (const float*)d_in[9];
    float* out = (float*)d_out;

    int* ws = (int*)d_ws;
    int*   deg  = ws + OFF_DEG;
    int*   cur  = ws + OFF_CUR;
    int*   offs = ws + OFF_OFFS;
    int*   bsum = ws + OFF_BSUM;
    float* d2a  = (float*)(ws + OFF_D2);
    float* rda  = (float*)(ws + OFF_RD);
    float* dinva= (float*)(ws + OFF_DINV);
    int*   adj  = ws + OFF_ADJ;
    float* bufA = (float*)(ws + OFF_BUFA);   // h1, later gs2
    float* bufB = (float*)(ws + OFF_BUFB);   // gs0
    float* bufC = (float*)(ws + OFF_BUFC);   // gs1

    const int* srcp = ei;
    const int* dstp = ei + N_EDGES;

    hipMemsetAsync(deg, 0, NP * sizeof(int), stream);

    k_deg<<<(N_EDGES + 255) / 256, 256, 0, stream>>>(dstp, deg, N_EDGES);
    k_scan_a<<<NB_SCAN, 256, 0, stream>>>(deg, offs, bsum);
    k_scan_b<<<1, 128, 0, stream>>>(bsum, offs);
    k_scan_c<<<NB_SCAN, 256, 0, stream>>>(deg, offs, bsum, cur, d2a, rda, dinva);
    k_fill<<<(N_EDGES + 255) / 256, 256, 0, stream>>>(srcp, dstp, cur, adj, N_EDGES);

    int nblk = (N_NODES + 63) / 64;   // 1563
    k_gemm1<<<nblk, 256, 0, stream>>>(x, W1, b1, bufA, N_NODES);
    k_gemm2s<<<nblk, 256, 0, stream>>>(bufA, W2, b2, dinva, bufB, N_NODES);  // gs0

    k_prop<<<(N_NODES + 3) / 4, 256, 0, stream>>>(bufB, bufC, offs, adj, d2a, N_NODES); // gs1
    k_prop<<<(N_NODES + 3) / 4, 256, 0, stream>>>(bufC, bufA, offs, adj, d2a, N_NODES); // gs2

    k_final<<<nblk, 256, 0, stream>>>(bufB, bufC, bufA, Wm1, bm1, Wm2, bm2, rda, out, N_NODES);
}

// Round 4
// 360.062 us; speedup vs baseline: 2.2951x; 1.4305x over previous
//
#include <hip/hip_runtime.h>
#include <math.h>

#define N_NODES 100000
#define N_EDGES 1600000
#define IN_F 128
#define H_F 64
#define KP 68        // padded LDS leading dim for A tiles

#define NBKT 196     // ceil(100000/512) buckets of 512 nodes
#define BSEG 16384   // per-bucket segment capacity (mean 8163, +91 sigma)
#define BCAP 14336   // LDS staging capacity for adj per bucket (56KB)

// workspace layout in 4-byte words
#define NP        100096
#define OFF_CNT   0                           // int[256]
#define OFF_BBASE 256                         // int[256]
#define OFF_OFFS  512                         // int[N+1] (NP+64)
#define OFF_D2    (512 + NP + 64)             // float[NP]
#define OFF_RD    (OFF_D2 + NP)               // float[NP]
#define OFF_DINV  (OFF_RD + NP)               // float[NP]
#define OFF_ADJ   (OFF_DINV + NP)             // int[N_EDGES]
#define OFF_BUFA  (OFF_ADJ + N_EDGES)         // float[N*64]  h1 / gs2; binned aliases here
#define OFF_BUFB  (OFF_BUFA + N_NODES*H_F)    // float[N*64]  gs0
#define OFF_BUFC  (OFF_BUFB + N_NODES*H_F)    // float[N*64]  gs1
// binned needs 196*16384 = 3,211,264 words <= N*64 = 6,400,000 words (bufA) OK

// ---- pass A: bin edges by dst>>9, packed (local<<17 | src) ----
__global__ __launch_bounds__(256) void k_bin(const int* __restrict__ src,
        const int* __restrict__ dst, int* __restrict__ cnt,
        int* __restrict__ binned, int E) {
    __shared__ int hist[NBKT];
    __shared__ int curb[NBKT];
    int t = threadIdx.x;
    for (int i = t; i < NBKT; i += 256) hist[i] = 0;
    __syncthreads();
    int base = blockIdx.x * 4096 + t;
    int d[16];
    #pragma unroll
    for (int i = 0; i < 16; ++i) {
        int e = base + i * 256;
        int dd = (e < E) ? dst[e] : -1;
        d[i] = dd;
        if (dd >= 0) atomicAdd(&hist[dd >> 9], 1);
    }
    __syncthreads();
    for (int i = t; i < NBKT; i += 256) {
        int h = hist[i];
        curb[i] = (h > 0) ? atomicAdd(&cnt[i], h) : 0;
    }
    __syncthreads();
    #pragma unroll
    for (int i = 0; i < 16; ++i) {
        int e = base + i * 256;
        if (e < E) {
            int s = src[e];
            int dd = d[i];
            int b = dd >> 9;
            int p = atomicAdd(&curb[b], 1);
            if (p < BSEG) binned[b * BSEG + p] = ((dd & 511) << 17) | s;
        }
    }
}

// ---- pass B: exclusive scan of bucket counts ----
__global__ __launch_bounds__(256) void k_bscan(const int* __restrict__ cnt,
        int* __restrict__ bbase, int* __restrict__ offs) {
    __shared__ int sm[256];
    int t = threadIdx.x;
    int v = (t < NBKT) ? cnt[t] : 0;
    sm[t] = v;
    __syncthreads();
    #pragma unroll
    for (int off = 1; off < 256; off <<= 1) {
        int u = (t >= off) ? sm[t - off] : 0;
        __syncthreads();
        sm[t] += u;
        __syncthreads();
    }
    if (t < NBKT) bbase[t] = sm[t] - v;
    if (t == 0) offs[N_NODES] = N_EDGES;
}

// ---- pass C: per-bucket CSR fill with LDS staging + degree-derived arrays ----
__global__ __launch_bounds__(256) void k_cfill(const int* __restrict__ binned,
        const int* __restrict__ cnt, const int* __restrict__ bbase,
        int* __restrict__ offs, int* __restrict__ adj,
        float* __restrict__ d2a, float* __restrict__ rda, float* __restrict__ dinva) {
    __shared__ int degl[512];
    __shared__ int offl[512];
    __shared__ int curl[512];
    __shared__ int wsum[4];
    __shared__ int adjl[BCAP];
    int b = blockIdx.x, t = threadIdx.x;
    int n0 = b << 9;
    int cntb = cnt[b];
    int baseb = bbase[b];
    const int* bp = binned + b * BSEG;
    degl[2 * t] = 0; degl[2 * t + 1] = 0;
    __syncthreads();
    for (int i = t; i < cntb; i += 256) {
        int w = bp[i];
        atomicAdd(&degl[w >> 17], 1);
    }
    __syncthreads();
    // 512-elem exclusive scan with 256 threads
    int d0 = degl[2 * t], d1 = degl[2 * t + 1];
    int tot = d0 + d1;
    int lane = t & 63, wid = t >> 6;
    int inc = tot;
    #pragma unroll
    for (int off = 1; off < 64; off <<= 1) {
        int v = __shfl_up(inc, off, 64);
        if (lane >= off) inc += v;
    }
    if (lane == 63) wsum[wid] = inc;
    __syncthreads();
    int wb = 0;
    for (int w = 0; w < wid; ++w) wb += wsum[w];
    int excl = wb + inc - tot;
    offl[2 * t] = excl;       curl[2 * t] = excl;
    offl[2 * t + 1] = excl + d0; curl[2 * t + 1] = excl + d0;
    __syncthreads();
    // node outputs
    #pragma unroll
    for (int rep = 0; rep < 2; ++rep) {
        int i = t + rep * 256;
        int n = n0 + i;
        if (n < N_NODES) {
            offs[n] = baseb + offl[i];
            float df = (float)degl[i];
            if (df < 1.f) df = 1.f;
            float di = 1.0f / sqrtf(df);
            dinva[n] = di;
            d2a[n] = di * di;
            rda[n] = sqrtf(df);
        }
    }
    // scatter into LDS staging
    for (int i = t; i < cntb; i += 256) {
        int w = bp[i];
        int loc = w >> 17;
        int s = w & 0x1FFFF;
        int p = atomicAdd(&curl[loc], 1);
        if (p < BCAP) adjl[p] = s;
        else adj[baseb + p] = s;   // statistically never
    }
    __syncthreads();
    // coalesced dump
    int lim = cntb < BCAP ? cntb : BCAP;
    for (int i = t; i < lim; i += 256) adj[baseb + i] = adjl[i];
}

// ================= tiled GEMMs: 64 nodes x 64 outs per 256-thr block ========
__global__ __launch_bounds__(256) void k_gemm1(const float* __restrict__ x,
        const float* __restrict__ W, const float* __restrict__ b,
        float* __restrict__ h, int N) {
    __shared__ float Al[64 * KP];
    __shared__ float Bl[64 * 64];
    int t = threadIdx.x;
    int tx = t & 15, ty = t >> 4;
    int nb = blockIdx.x * 64;
    float acc[4][4] = {{0}};
    for (int p = 0; p < 2; ++p) {
        #pragma unroll
        for (int pp = 0; pp < 4; ++pp) {
            int nl = ty + 16 * pp;
            int nn = nb + nl; if (nn >= N) nn = N - 1;
            float4 v = ((const float4*)(x + (size_t)nn * IN_F + p * 64))[tx];
            *(float4*)&Al[nl * KP + 4 * tx] = v;
        }
        #pragma unroll
        for (int pp = 0; pp < 4; ++pp) {
            int k = ty + 16 * pp;
            float4 v = ((const float4*)(W + (size_t)(p * 64 + k) * 64))[tx];
            *(float4*)&Bl[k * 64 + 4 * tx] = v;
        }
        __syncthreads();
        #pragma unroll 4
        for (int k = 0; k < 64; ++k) {
            float a0 = Al[(4 * ty + 0) * KP + k];
            float a1 = Al[(4 * ty + 1) * KP + k];
            float a2 = Al[(4 * ty + 2) * KP + k];
            float a3 = Al[(4 * ty + 3) * KP + k];
            float4 bv = *(const float4*)&Bl[k * 64 + 4 * tx];
            acc[0][0] = fmaf(a0, bv.x, acc[0][0]); acc[0][1] = fmaf(a0, bv.y, acc[0][1]);
            acc[0][2] = fmaf(a0, bv.z, acc[0][2]); acc[0][3] = fmaf(a0, bv.w, acc[0][3]);
            acc[1][0] = fmaf(a1, bv.x, acc[1][0]); acc[1][1] = fmaf(a1, bv.y, acc[1][1]);
            acc[1][2] = fmaf(a1, bv.z, acc[1][2]); acc[1][3] = fmaf(a1, bv.w, acc[1][3]);
            acc[2][0] = fmaf(a2, bv.x, acc[2][0]); acc[2][1] = fmaf(a2, bv.y, acc[2][1]);
            acc[2][2] = fmaf(a2, bv.z, acc[2][2]); acc[2][3] = fmaf(a2, bv.w, acc[2][3]);
            acc[3][0] = fmaf(a3, bv.x, acc[3][0]); acc[3][1] = fmaf(a3, bv.y, acc[3][1]);
            acc[3][2] = fmaf(a3, bv.z, acc[3][2]); acc[3][3] = fmaf(a3, bv.w, acc[3][3]);
        }
        __syncthreads();
    }
    float4 bias = ((const float4*)b)[tx];
    #pragma unroll
    for (int i = 0; i < 4; ++i) {
        int n = nb + 4 * ty + i;
        if (n < N) {
            float4 r;
            r.x = fmaxf(acc[i][0] + bias.x, 0.f);
            r.y = fmaxf(acc[i][1] + bias.y, 0.f);
            r.z = fmaxf(acc[i][2] + bias.z, 0.f);
            r.w = fmaxf(acc[i][3] + bias.w, 0.f);
            ((float4*)(h + (size_t)n * 64))[tx] = r;
        }
    }
}

__global__ __launch_bounds__(256) void k_gemm2s(const float* __restrict__ hin,
        const float* __restrict__ W, const float* __restrict__ b,
        const float* __restrict__ dinva, float* __restrict__ gs, int N) {
    __shared__ float Al[64 * KP];
    __shared__ float Bl[64 * 64];
    int t = threadIdx.x;
    int tx = t & 15, ty = t >> 4;
    int nb = blockIdx.x * 64;
    float acc[4][4] = {{0}};
    #pragma unroll
    for (int pp = 0; pp < 4; ++pp) {
        int nl = ty + 16 * pp;
        int nn = nb + nl; if (nn >= N) nn = N - 1;
        float4 v = ((const float4*)(hin + (size_t)nn * 64))[tx];
        *(float4*)&Al[nl * KP + 4 * tx] = v;
        int k = nl;
        float4 w = ((const float4*)(W + (size_t)k * 64))[tx];
        *(float4*)&Bl[k * 64 + 4 * tx] = w;
    }
    __syncthreads();
    #pragma unroll 4
    for (int k = 0; k < 64; ++k) {
        float a0 = Al[(4 * ty + 0) * KP + k];
        float a1 = Al[(4 * ty + 1) * KP + k];
        float a2 = Al[(4 * ty + 2) * KP + k];
        float a3 = Al[(4 * ty + 3) * KP + k];
        float4 bv = *(const float4*)&Bl[k * 64 + 4 * tx];
        acc[0][0] = fmaf(a0, bv.x, acc[0][0]); acc[0][1] = fmaf(a0, bv.y, acc[0][1]);
        acc[0][2] = fmaf(a0, bv.z, acc[0][2]); acc[0][3] = fmaf(a0, bv.w, acc[0][3]);
        acc[1][0] = fmaf(a1, bv.x, acc[1][0]); acc[1][1] = fmaf(a1, bv.y, acc[1][1]);
        acc[1][2] = fmaf(a1, bv.z, acc[1][2]); acc[1][3] = fmaf(a1, bv.w, acc[1][3]);
        acc[2][0] = fmaf(a2, bv.x, acc[2][0]); acc[2][1] = fmaf(a2, bv.y, acc[2][1]);
        acc[2][2] = fmaf(a2, bv.z, acc[2][2]); acc[2][3] = fmaf(a2, bv.w, acc[2][3]);
        acc[3][0] = fmaf(a3, bv.x, acc[3][0]); acc[3][1] = fmaf(a3, bv.y, acc[3][1]);
        acc[3][2] = fmaf(a3, bv.z, acc[3][2]); acc[3][3] = fmaf(a3, bv.w, acc[3][3]);
    }
    float4 bias = ((const float4*)b)[tx];
    #pragma unroll
    for (int i = 0; i < 4; ++i) {
        int n = nb + 4 * ty + i;
        if (n < N) {
            float di = dinva[n];
            float4 r;
            r.x = di * fmaxf(acc[i][0] + bias.x, 0.f);
            r.y = di * fmaxf(acc[i][1] + bias.y, 0.f);
            r.z = di * fmaxf(acc[i][2] + bias.z, 0.f);
            r.w = di * fmaxf(acc[i][3] + bias.w, 0.f);
            ((float4*)(gs + (size_t)n * 64))[tx] = r;
        }
    }
}

// ---- propagation: gs_out = gs - d2[n] * sum_src gs[src], unroll x4 ----
__global__ __launch_bounds__(256) void k_prop(const float* __restrict__ gs,
        float* __restrict__ gsn, const int* __restrict__ offs,
        const int* __restrict__ adj, const float* __restrict__ d2a, int N) {
    int t = threadIdx.x;
    int lane = t & 63;
    int g = lane >> 4;
    int q = lane & 15;
    int n = blockIdx.x * 4 + (t >> 6);
    if (n >= N) return;
    int beg = offs[n], end = offs[n + 1];
    const float4* gs4 = (const float4*)gs;
    float ax = 0.f, ay = 0.f, az = 0.f, aw = 0.f;
    int e = beg + g;
    for (; e + 12 < end; e += 16) {
        int s0 = adj[e], s1 = adj[e + 4], s2 = adj[e + 8], s3 = adj[e + 12];
        float4 f0 = gs4[(size_t)s0 * 16 + q];
        float4 f1 = gs4[(size_t)s1 * 16 + q];
        float4 f2 = gs4[(size_t)s2 * 16 + q];
        float4 f3 = gs4[(size_t)s3 * 16 + q];
        ax += (f0.x + f1.x) + (f2.x + f3.x);
        ay += (f0.y + f1.y) + (f2.y + f3.y);
        az += (f0.z + f1.z) + (f2.z + f3.z);
        aw += (f0.w + f1.w) + (f2.w + f3.w);
    }
    for (; e < end; e += 4) {
        int s = adj[e];
        float4 f = gs4[(size_t)s * 16 + q];
        ax += f.x; ay += f.y; az += f.z; aw += f.w;
    }
    ax += __shfl_xor(ax, 16); ay += __shfl_xor(ay, 16);
    az += __shfl_xor(az, 16); aw += __shfl_xor(aw, 16);
    ax += __shfl_xor(ax, 32); ay += __shfl_xor(ay, 32);
    az += __shfl_xor(az, 32); aw += __shfl_xor(aw, 32);
    if (g == 0) {
        float d2n = d2a[n];
        float4 self = gs4[(size_t)n * 16 + q];
        float4 r;
        r.x = fmaf(-d2n, ax, self.x);
        r.y = fmaf(-d2n, ay, self.y);
        r.z = fmaf(-d2n, az, self.z);
        r.w = fmaf(-d2n, aw, self.w);
        ((float4*)gsn)[(size_t)n * 16 + q] = r;
    }
}

// ---- final fused head ----
__global__ __launch_bounds__(256) void k_final(const float* __restrict__ gs0,
        const float* __restrict__ gs1, const float* __restrict__ gs2,
        const float* __restrict__ Wm1, const float* __restrict__ bm1,
        const float* __restrict__ Wm2, const float* __restrict__ bm2,
        const float* __restrict__ rda, float* __restrict__ out, int N) {
    __shared__ float Al[64 * KP];
    __shared__ float Bl[64 * 64];
    int t = threadIdx.x;
    int tx = t & 15, ty = t >> 4;
    int nb = blockIdx.x * 64;
    const float* bufs[3] = {gs0, gs1, gs2};
    float acc[4][4] = {{0}};
    for (int p = 0; p < 3; ++p) {
        const float* gp = bufs[p];
        #pragma unroll
        for (int pp = 0; pp < 4; ++pp) {
            int nl = ty + 16 * pp;
            int nn = nb + nl; if (nn >= N) nn = N - 1;
            float4 v = ((const float4*)(gp + (size_t)nn * 64))[tx];
            *(float4*)&Al[nl * KP + 4 * tx] = v;
            int k = nl;
            float4 w0 = ((const float4*)(Wm1 + (size_t)k * 64))[tx];
            float4 w1 = ((const float4*)(Wm1 + (size_t)(64 + k) * 64))[tx];
            float4 w2 = ((const float4*)(Wm1 + (size_t)(128 + k) * 64))[tx];
            float4 mv;
            if (p == 0) {
                mv.x = 3.0f * w0.x; mv.y = 3.0f * w0.y;
                mv.z = 3.0f * w0.z; mv.w = 3.0f * w0.w;
            } else if (p == 1) {
                mv.x = fmaf(-3.0f, w0.x, 3.0f * w1.x);
                mv.y = fmaf(-3.0f, w0.y, 3.0f * w1.y);
                mv.z = fmaf(-3.0f, w0.z, 3.0f * w1.z);
                mv.w = fmaf(-3.0f, w0.w, 3.0f * w1.w);
            } else {
                mv.x = 0.75f * (w0.x + w2.x) - 1.5f * w1.x;
                mv.y = 0.75f * (w0.y + w2.y) - 1.5f * w1.y;
                mv.z = 0.75f * (w0.z + w2.z) - 1.5f * w1.z;
                mv.w = 0.75f * (w0.w + w2.w) - 1.5f * w1.w;
            }
            *(float4*)&Bl[k * 64 + 4 * tx] = mv;
        }
        __syncthreads();
        #pragma unroll 4
        for (int k = 0; k < 64; ++k) {
            float a0 = Al[(4 * ty + 0) * KP + k];
            float a1 = Al[(4 * ty + 1) * KP + k];
            float a2 = Al[(4 * ty + 2) * KP + k];
            float a3 = Al[(4 * ty + 3) * KP + k];
            float4 bv = *(const float4*)&Bl[k * 64 + 4 * tx];
            acc[0][0] = fmaf(a0, bv.x, acc[0][0]); acc[0][1] = fmaf(a0, bv.y, acc[0][1]);
            acc[0][2] = fmaf(a0, bv.z, acc[0][2]); acc[0][3] = fmaf(a0, bv.w, acc[0][3]);
            acc[1][0] = fmaf(a1, bv.x, acc[1][0]); acc[1][1] = fmaf(a1, bv.y, acc[1][1]);
            acc[1][2] = fmaf(a1, bv.z, acc[1][2]); acc[1][3] = fmaf(a1, bv.w, acc[1][3]);
            acc[2][0] = fmaf(a2, bv.x, acc[2][0]); acc[2][1] = fmaf(a2, bv.y, acc[2][1]);
            acc[2][2] = fmaf(a2, bv.z, acc[2][2]); acc[2][3] = fmaf(a2, bv.w, acc[2][3]);
            acc[3][0] = fmaf(a3, bv.x, acc[3][0]); acc[3][1] = fmaf(a3, bv.y, acc[3][1]);
            acc[3][2] = fmaf(a3, bv.z, acc[3][2]); acc[3][3] = fmaf(a3, bv.w, acc[3][3]);
        }
        __syncthreads();
    }
    float4 bmv = ((const float4*)bm1)[tx];
    float4 wa = ((const float4*)Wm2)[2 * tx];
    float4 wb = ((const float4*)Wm2)[2 * tx + 1];
    float bo0 = bm2[0], bo1 = bm2[1];
    #pragma unroll
    for (int i = 0; i < 4; ++i) {
        int n = nb + 4 * ty + i;
        float rdn = rda[(n < N) ? n : (N - 1)];
        float h0 = fmaxf(fmaf(rdn, acc[i][0], bmv.x), 0.f);
        float h1 = fmaxf(fmaf(rdn, acc[i][1], bmv.y), 0.f);
        float h2 = fmaxf(fmaf(rdn, acc[i][2], bmv.z), 0.f);
        float h3 = fmaxf(fmaf(rdn, acc[i][3], bmv.w), 0.f);
        float p0 = h0 * wa.x + h1 * wa.z + h2 * wb.x + h3 * wb.z;
        float p1 = h0 * wa.y + h1 * wa.w + h2 * wb.y + h3 * wb.w;
        #pragma unroll
        for (int m = 1; m < 16; m <<= 1) {
            p0 += __shfl_xor(p0, m);
            p1 += __shfl_xor(p1, m);
        }
        if (tx == 0 && n < N) {
            out[(size_t)n * 2 + 0] = p0 + bo0;
            out[(size_t)n * 2 + 1] = p1 + bo1;
        }
    }
}

extern "C" void kernel_launch(void* const* d_in, const int* in_sizes, int n_in,
                              void* d_out, int out_size, void* d_ws, size_t ws_size,
                              hipStream_t stream) {
    const float* x   = (const float*)d_in[0];
    const int*   ei  = (const int*)d_in[1];
    const float* W1  = (const float*)d_in[2];
    const float* b1  = (const float*)d_in[3];
    const float* W2  = (const float*)d_in[4];
    const float* b2  = (const float*)d_in[5];
    const float* Wm1 = (const float*)d_in[6];
    const float* bm1 = (const float*)d_in[7];
    const float* Wm2 = (const float*)d_in[8];
    const float* bm2 = (const float*)d_in[9];
    float* out = (float*)d_out;

    int* ws = (int*)d_ws;
    int*   cnt   = ws + OFF_CNT;
    int*   bbase = ws + OFF_BBASE;
    int*   offs  = ws + OFF_OFFS;
    float* d2a   = (float*)(ws + OFF_D2);
    float* rda   = (float*)(ws + OFF_RD);
    float* dinva = (float*)(ws + OFF_DINV);
    int*   adj   = ws + OFF_ADJ;
    float* bufA  = (float*)(ws + OFF_BUFA);   // h1, later gs2
    float* bufB  = (float*)(ws + OFF_BUFB);   // gs0
    float* bufC  = (float*)(ws + OFF_BUFC);   // gs1
    int*   binned = (int*)bufA;               // dead before gemm1 writes bufA

    const int* srcp = ei;
    const int* dstp = ei + N_EDGES;

    hipMemsetAsync(cnt, 0, 256 * sizeof(int), stream);

    k_bin<<<(N_EDGES + 4095) / 4096, 256, 0, stream>>>(srcp, dstp, cnt, binned, N_EDGES);
    k_bscan<<<1, 256, 0, stream>>>(cnt, bbase, offs);
    k_cfill<<<NBKT, 256, 0, stream>>>(binned, cnt, bbase, offs, adj, d2a, rda, dinva);

    int nblk = (N_NODES + 63) / 64;
    k_gemm1<<<nblk, 256, 0, stream>>>(x, W1, b1, bufA, N_NODES);
    k_gemm2s<<<nblk, 256, 0, stream>>>(bufA, W2, b2, dinva, bufB, N_NODES);  // gs0

    k_prop<<<(N_NODES + 3) / 4, 256, 0, stream>>>(bufB, bufC, offs, adj, d2a, N_NODES); // gs1
    k_prop<<<(N_NODES + 3) / 4, 256, 0, stream>>>(bufC, bufA, offs, adj, d2a, N_NODES); // gs2

    k_final<<<nblk, 256, 0, stream>>>(bufB, bufC, bufA, Wm1, bm1, Wm2, bm2, rda, out, N_NODES);
}